// Round 1
// baseline (6877.219 us; speedup 1.0000x reference)
//
#include <hip/hip_runtime.h>

// SiameseEdgeConvNet: 2-layer EdgeConv (max aggr) on two graphs, shared weights.
// N=50000, E=1.6e6, dims 32 -> 64 -> 64.
//
// Math notes (exactness):
//  * [xi, xj-xi] @ W == xi @ (W_lo - W_hi) + xj @ W_hi   (A/B precompute)
//  * messages are post-ReLU >= 0  ->  segment_max == uint-bitwise atomicMax
//    with zero-init (non-neg IEEE floats order-isomorphic to their bits);
//    empty segments stay 0 == reference's isfinite->0 fixup.
//  * PReLU sees only >=0 inputs (max of ReLUs) -> identity -> skipped.

constexpr int HID = 64;

template<int K>
__global__ __launch_bounds__(256) void edge_kernel(
    const float* __restrict__ x,      // [N, K]
    const int*   __restrict__ src,    // [E]
    const int*   __restrict__ dst,    // [E]
    const float* __restrict__ W,      // [2K, 64] row-major
    const float* __restrict__ bias,   // [64]
    unsigned int* __restrict__ agg,   // [N*64], pre-zeroed, float bits
    int nEdges)
{
    const int lane   = threadIdx.x & 63;
    const int wid    = (blockIdx.x * blockDim.x + threadIdx.x) >> 6;
    const int nWaves = (gridDim.x * blockDim.x) >> 6;

    // Per-lane weight column (lane = output channel).
    // a_reg = W_lo - W_hi (multiplies xi), b_reg = W_hi (multiplies xj).
    float a_reg[K], b_reg[K];
    #pragma unroll
    for (int k = 0; k < K; ++k) {
        float wlo = W[k * HID + lane];
        float whi = W[(K + k) * HID + lane];
        a_reg[k] = wlo - whi;
        b_reg[k] = whi;
    }
    const float bv = bias[lane];

    for (int base = wid * 64; base < nEdges; base += nWaves * 64) {
        const int myE = base + lane;
        const int sv = (myE < nEdges) ? src[myE] : 0;   // staged 64 edges/wave
        const int dv = (myE < nEdges) ? dst[myE] : 0;
        const int cnt = min(64, nEdges - base);

        for (int i = 0; i < cnt; ++i) {
            const int s = __shfl(sv, i);
            const int d = __shfl(dv, i);
            float acc = bv;

            if constexpr (K == 32) {
                // lanes 0..31 hold xi, lanes 32..63 hold xj
                const float xv = (lane < 32) ? x[d * 32 + lane]
                                             : x[s * 32 + (lane - 32)];
                #pragma unroll
                for (int k = 0; k < 32; ++k) {
                    const float xik = __shfl(xv, k);
                    const float xjk = __shfl(xv, 32 + k);
                    acc = fmaf(xik, a_reg[k], acc);
                    acc = fmaf(xjk, b_reg[k], acc);
                }
            } else {
                const float xiv = x[(size_t)d * 64 + lane];
                const float xjv = x[(size_t)s * 64 + lane];
                #pragma unroll
                for (int k = 0; k < 64; ++k) {
                    const float xik = __shfl(xiv, k);
                    const float xjk = __shfl(xjv, k);
                    acc = fmaf(xik, a_reg[k], acc);
                    acc = fmaf(xjk, b_reg[k], acc);
                }
            }

            const float m = fmaxf(acc, 0.0f);
            if (m > 0.0f)  // atomicMax with 0 is a no-op vs zero-init: skip
                atomicMax(&agg[(size_t)d * HID + lane], __float_as_uint(m));
        }
    }
}

extern "C" void kernel_launch(void* const* d_in, const int* in_sizes, int n_in,
                              void* d_out, int out_size, void* d_ws, size_t ws_size,
                              hipStream_t stream) {
    const float* x1  = (const float*)d_in[0];
    const int*   ei1 = (const int*)d_in[1];   // [2, E] row-major: src then dst
    const float* x2  = (const float*)d_in[2];
    const int*   ei2 = (const int*)d_in[3];
    const float* W1  = (const float*)d_in[4];
    const float* b1  = (const float*)d_in[5];
    // d_in[6] = prelu_a: unused (PReLU is identity on >=0 inputs)
    const float* W2  = (const float*)d_in[7];
    const float* b2  = (const float*)d_in[8];

    const int N = in_sizes[0] / 32;
    const int E = in_sizes[1] / 2;

    float*        h   = (float*)d_ws;          // [N, 64] hidden, reused per graph
    unsigned int* h_u = (unsigned int*)d_ws;
    float*        out = (float*)d_out;         // e1 then e2, each [N, 64]

    const int waves  = (E + 63) / 64;
    const int blocks = (waves + 3) / 4;        // 256 threads = 4 waves/block

    for (int g = 0; g < 2; ++g) {
        const float* x  = g ? x2 : x1;
        const int*   ei = g ? ei2 : ei1;
        unsigned int* out_u = (unsigned int*)(out + (size_t)g * N * HID);

        hipMemsetAsync(h_u, 0, (size_t)N * HID * sizeof(float), stream);
        edge_kernel<32><<<blocks, 256, 0, stream>>>(x, ei, ei + E, W1, b1, h_u, E);
        hipMemsetAsync(out_u, 0, (size_t)N * HID * sizeof(float), stream);
        edge_kernel<64><<<blocks, 256, 0, stream>>>(h, ei, ei + E, W2, b2, out_u, E);
    }
}

// Round 2
// 964.721 us; speedup vs baseline: 7.1287x; 7.1287x over previous
//
#include <hip/hip_runtime.h>
#include <cfloat>

// SiameseEdgeConvNet: 2-layer EdgeConv (max aggr) on two graphs, shared weights.
// N=50000, E=1.6e6, dims 32 -> 64 -> 64.
//
// Algebraic restructure (exact in real arithmetic):
//   msg = relu([xi, xj-xi] @ W + b) = relu(xi@A + xj@B + b),  A=W_lo-W_hi, B=W_hi
//   Let u = x@A + b (per node), v = x@B (per node).
//   ReLU monotone => segment_max_e relu(u[d]+v[s_e]) = relu(u[d] + segment_max_e v[s_e])
//   => edge phase is a pure gather-max of v rows (no per-edge GEMM, no atomics
//      with CSR), node phase is two tiny GEMMs.
//   Empty segments (beg==end) -> 0, matching jax's isfinite->0 fixup.
//   PReLU input >= 0 (max of relus) -> identity -> skipped.

constexpr int HID = 64;

// ---------------- CSR build ----------------

__global__ void count_kernel(const int* __restrict__ dst, int* __restrict__ counts, int E) {
    int i = blockIdx.x * blockDim.x + threadIdx.x;
    int stride = gridDim.x * blockDim.x;
    for (; i < E; i += stride) atomicAdd(&counts[dst[i]], 1);
}

// Single-block exclusive scan: counts[N] -> row_ptr[N+1]
__global__ __launch_bounds__(1024) void scan_kernel(const int* __restrict__ counts,
                                                    int* __restrict__ row_ptr, int N) {
    __shared__ int bufA[1024], bufB[1024];
    const int t = threadIdx.x;
    const int chunk = (N + 1023) / 1024;
    const int beg = t * chunk, end = min(N, beg + chunk);
    int s = 0;
    for (int i = beg; i < end; ++i) s += counts[i];
    bufA[t] = s;
    __syncthreads();
    int* in = bufA; int* out = bufB;
    for (int off = 1; off < 1024; off <<= 1) {
        out[t] = in[t] + (t >= off ? in[t - off] : 0);
        __syncthreads();
        int* tmp = in; in = out; out = tmp;
    }
    int run = (t == 0) ? 0 : in[t - 1];
    for (int i = beg; i < end; ++i) { row_ptr[i] = run; run += counts[i]; }
    if (t == 0) row_ptr[N] = in[1023];
}

__global__ void scatter_kernel(const int* __restrict__ src, const int* __restrict__ dst,
                               int* __restrict__ wp, int* __restrict__ srcs, int E) {
    int i = blockIdx.x * blockDim.x + threadIdx.x;
    int stride = gridDim.x * blockDim.x;
    for (; i < E; i += stride) {
        int pos = atomicAdd(&wp[dst[i]], 1);
        srcs[pos] = src[i];
    }
}

// ---------------- node GEMM: u = x@A + b, v = x@B ----------------
// lane = output channel; weight columns in registers; x row broadcast via shfl.

template<int K>
__global__ __launch_bounds__(256) void gemm_uv_kernel(
    const float* __restrict__ x,      // [N, K]
    const float* __restrict__ W,      // [2K, 64] row-major
    const float* __restrict__ bias,   // [64]
    float* __restrict__ u,            // [N, 64]
    float* __restrict__ v,            // [N, 64]
    int N)
{
    const int lane = threadIdx.x & 63;
    const int wid  = (blockIdx.x * blockDim.x + threadIdx.x) >> 6;
    const int nW   = (gridDim.x * blockDim.x) >> 6;

    float a_reg[K], b_reg[K];
    #pragma unroll
    for (int k = 0; k < K; ++k) {
        float wlo = W[k * HID + lane];
        float whi = W[(K + k) * HID + lane];
        a_reg[k] = wlo - whi;
        b_reg[k] = whi;
    }
    const float bv = bias[lane];

    for (int n = wid; n < N; n += nW) {
        const float xr = x[(size_t)n * K + (lane & (K - 1))];
        float uu = bv, vv = 0.f;
        #pragma unroll
        for (int k = 0; k < K; ++k) {
            const float xk = __shfl(xr, k);
            uu = fmaf(xk, a_reg[k], uu);
            vv = fmaf(xk, b_reg[k], vv);
        }
        u[(size_t)n * HID + lane] = uu;
        v[(size_t)n * HID + lane] = vv;
    }
}

// ---------------- edge phase: out[d] = relu(u[d] + max_{e in CSR[d]} v[srcs[e]]) ----------------
// 16 threads per node, float4 per thread = 64 channels. Register max-accumulate,
// one coalesced row-write per node, zero atomics.

__global__ __launch_bounds__(256) void edge_max_kernel(
    const float* __restrict__ u,
    const float* __restrict__ v,
    const int*   __restrict__ row_ptr,
    const int*   __restrict__ srcs,
    float* __restrict__ out,
    int N)
{
    const int node = blockIdx.x * 16 + (threadIdx.x >> 4);
    const int sub  = threadIdx.x & 15;
    if (node >= N) return;

    const int beg = row_ptr[node], end = row_ptr[node + 1];
    const float4* __restrict__ v4 = (const float4*)v;

    float4 m = make_float4(-FLT_MAX, -FLT_MAX, -FLT_MAX, -FLT_MAX);
    int e = beg;
    // 2-way unroll: two independent gathers in flight per iteration
    for (; e + 1 < end; e += 2) {
        const int s0 = srcs[e], s1 = srcs[e + 1];
        const float4 a = v4[(size_t)s0 * 16 + sub];
        const float4 b = v4[(size_t)s1 * 16 + sub];
        m.x = fmaxf(m.x, fmaxf(a.x, b.x));
        m.y = fmaxf(m.y, fmaxf(a.y, b.y));
        m.z = fmaxf(m.z, fmaxf(a.z, b.z));
        m.w = fmaxf(m.w, fmaxf(a.w, b.w));
    }
    if (e < end) {
        const int s0 = srcs[e];
        const float4 a = v4[(size_t)s0 * 16 + sub];
        m.x = fmaxf(m.x, a.x); m.y = fmaxf(m.y, a.y);
        m.z = fmaxf(m.z, a.z); m.w = fmaxf(m.w, a.w);
    }

    float4 r;
    if (beg == end) {
        r = make_float4(0.f, 0.f, 0.f, 0.f);   // no in-edges: isfinite->0 path
    } else {
        const float4 uu = ((const float4*)u)[(size_t)node * 16 + sub];
        r.x = fmaxf(uu.x + m.x, 0.f);
        r.y = fmaxf(uu.y + m.y, 0.f);
        r.z = fmaxf(uu.z + m.z, 0.f);
        r.w = fmaxf(uu.w + m.w, 0.f);
    }
    ((float4*)out)[(size_t)node * 16 + sub] = r;
}

// ---------------- orchestration ----------------

extern "C" void kernel_launch(void* const* d_in, const int* in_sizes, int n_in,
                              void* d_out, int out_size, void* d_ws, size_t ws_size,
                              hipStream_t stream) {
    const float* x1  = (const float*)d_in[0];
    const int*   ei1 = (const int*)d_in[1];   // [2, E]: src row then dst row
    const float* x2  = (const float*)d_in[2];
    const int*   ei2 = (const int*)d_in[3];
    const float* W1  = (const float*)d_in[4];
    const float* b1  = (const float*)d_in[5];
    // d_in[6] = prelu_a: unused (identity on >=0)
    const float* W2  = (const float*)d_in[7];
    const float* b2  = (const float*)d_in[8];

    const int N = in_sizes[0] / 32;
    const int E = in_sizes[1] / 2;

    // workspace layout (16B-aligned chunks)
    char* ws = (char*)d_ws;
    float* u       = (float*)ws;                         ws += (size_t)N * HID * sizeof(float);
    float* v       = (float*)ws;                         ws += (size_t)N * HID * sizeof(float);
    float* h       = (float*)ws;                         ws += (size_t)N * HID * sizeof(float);
    int*   srcs    = (int*)ws;                           ws += (size_t)E * sizeof(int);
    int*   row_ptr = (int*)ws;                           ws += (size_t)(N + 1) * sizeof(int);
    int*   wp      = (int*)ws;                           ws += (size_t)N * sizeof(int);
    int*   counts  = (int*)ws;

    float* out = (float*)d_out;  // e1 then e2, each [N, 64]

    const int eBlocks = (E + 255) / 256;
    const int nBlocks = (N + 15) / 16;     // edge_max: 16 nodes/block? no: 16 thr/node, 16 nodes/block
    const int gBlocks = 1024;              // gemm: amortize weight-register loads

    for (int g = 0; g < 2; ++g) {
        const float* x   = g ? x2 : x1;
        const int*   ei  = g ? ei2 : ei1;
        const int*   src = ei;
        const int*   dst = ei + E;
        float* outg = out + (size_t)g * N * HID;

        // CSR build (shared by both layers)
        hipMemsetAsync(counts, 0, (size_t)N * sizeof(int), stream);
        count_kernel<<<eBlocks, 256, 0, stream>>>(dst, counts, E);
        scan_kernel<<<1, 1024, 0, stream>>>(counts, row_ptr, N);
        hipMemcpyAsync(wp, row_ptr, (size_t)N * sizeof(int),
                       hipMemcpyDeviceToDevice, stream);
        scatter_kernel<<<eBlocks, 256, 0, stream>>>(src, dst, wp, srcs, E);

        // layer 1: 32 -> 64
        gemm_uv_kernel<32><<<gBlocks, 256, 0, stream>>>(x, W1, b1, u, v, N);
        edge_max_kernel<<<nBlocks, 256, 0, stream>>>(u, v, row_ptr, srcs, h, N);

        // layer 2: 64 -> 64
        gemm_uv_kernel<64><<<gBlocks, 256, 0, stream>>>(h, W2, b2, u, v, N);
        edge_max_kernel<<<nBlocks, 256, 0, stream>>>(u, v, row_ptr, srcs, outg, N);
    }
}